// Round 14
// baseline (240.822 us; speedup 1.0000x reference)
//
#include <hip/hip_runtime.h>
#include <hip/hip_bf16.h>

typedef short bf16x8 __attribute__((ext_vector_type(8)));
typedef float f32x4 __attribute__((ext_vector_type(4)));
typedef float f32x16 __attribute__((ext_vector_type(16)));
typedef unsigned int u32x4 __attribute__((ext_vector_type(4)));

#define MFMA16(a, b, c) __builtin_amdgcn_mfma_f32_16x16x32_bf16((a), (b), (c), 0, 0, 0)
#define MFMA32(a, b, c) __builtin_amdgcn_mfma_f32_32x32x16_bf16((a), (b), (c), 0, 0, 0)

static __device__ __forceinline__ unsigned short f2bf(float f) {
  union { float f; unsigned u; } v;
  v.f = f;
  unsigned r = (v.u + 0x7FFFu + ((v.u >> 16) & 1u)) >> 16;
  return (unsigned short)r;
}

// round-half-up pack of two f32 -> bf16x2 word
static __device__ __forceinline__ unsigned pk2(float a, float b) {
  unsigned ua = __float_as_uint(a) + 0x8000u;
  unsigned ub = __float_as_uint(b) + 0x8000u;
  return (ua >> 16) | (ub & 0xFFFF0000u);
}

static __device__ __forceinline__ void gload16(const void* g, void* l) {
  __builtin_amdgcn_global_load_lds(
      (const __attribute__((address_space(1))) unsigned int*)g,
      (__attribute__((address_space(3))) unsigned int*)l, 16, 0, 0);
}

// ---------------- prep: 4 weight transposes + x cast, one launch ----------------
__global__ __launch_bounds__(256) void prep_all2(
    const float* __restrict__ x, unsigned short* __restrict__ Xb,
    const float* __restrict__ Wq, const float* __restrict__ Wk,
    const float* __restrict__ Wv, const float* __restrict__ Wo,
    unsigned short* __restrict__ WqT, unsigned short* __restrict__ WkT,
    unsigned short* __restrict__ WvT, unsigned short* __restrict__ WoT) {
  int id = blockIdx.x;
  if (id >= 10240) {
    const int n4 = (4096 * 2048) / 4;
    const int stride = 2048 * 256;
    for (int i = (id - 10240) * 256 + threadIdx.x; i < n4; i += stride) {
      float4 v = reinterpret_cast<const float4*>(x)[i];
      ushort4 o;
      o.x = f2bf(v.x); o.y = f2bf(v.y); o.z = f2bf(v.z); o.w = f2bf(v.w);
      reinterpret_cast<ushort4*>(Xb)[i] = o;
    }
    return;
  }
  __shared__ float tile[32][33];
  const float* src; unsigned short* dst; int R, C, bx, by;
  if (id < 4096)      { src = Wq; dst = WqT; R = 2048; C = 2048; bx = id & 63; by = id >> 6; }
  else if (id < 5120) { id -= 4096; src = Wk; dst = WkT; R = 2048; C = 512; bx = id & 15; by = id >> 4; }
  else if (id < 6144) { id -= 5120; src = Wv; dst = WvT; R = 2048; C = 512; bx = id & 15; by = id >> 4; }
  else                { id -= 6144; src = Wo; dst = WoT; R = 2048; C = 2048; bx = id & 63; by = id >> 6; }
  int tx = threadIdx.x & 31;
  int ty = threadIdx.x >> 5;
  int r0 = by * 32, c0 = bx * 32;
#pragma unroll
  for (int i = 0; i < 32; i += 8)
    tile[ty + i][tx] = src[(size_t)(r0 + ty + i) * C + (c0 + tx)];
  __syncthreads();
#pragma unroll
  for (int i = 0; i < 32; i += 8)
    dst[(size_t)(c0 + ty + i) * R + (r0 + tx)] = f2bf(tile[tx][ty + i]);
}

// ---------------- pipelined GEMM core: BM=256, BN=128, BK=64 ----------------
template <int EPI>
static __device__ __forceinline__ void g8p_core(
    const unsigned short* __restrict__ A, const unsigned short* __restrict__ B,
    unsigned short* __restrict__ Cb, unsigned short* __restrict__ Cb2,
    float* __restrict__ Cf, const float* __restrict__ bias,
    int N, int K, int bid, unsigned short* Al, unsigned short* Bl) {
  const int tid = threadIdx.x;
  const int wave = tid >> 6, lane = tid & 63;
  const int l15 = lane & 15, l4 = lane >> 4;
  const int tilesN = N >> 7;
  const int bm = bid / tilesN, bn = bid % tilesN;
  const int row0 = bm << 8, col0 = bn << 7;
  const int wr = (wave >> 1) << 6;
  const int wc = (wave & 1) << 6;

  const unsigned short* sA[4];
  const unsigned short* sB[2];
#pragma unroll
  for (int i = 0; i < 4; ++i) {
    int q = i * 512 + wave * 64 + lane;
    int r = q >> 3, c = (q & 7) ^ (r & 7);
    sA[i] = A + (size_t)(row0 + r) * K + c * 8;
  }
#pragma unroll
  for (int i = 0; i < 2; ++i) {
    int q = i * 512 + wave * 64 + lane;
    int r = q >> 3, c = (q & 7) ^ (r & 7);
    sB[i] = B + (size_t)(col0 + r) * K + c * 8;
  }

#define STG_H1(t_, bi)                                                      \
  { const size_t ko = (size_t)(t_) * 64;                                    \
    gload16(sA[0] + ko, &Al[(bi)*16384 + (0 * 512 + wave * 64) * 8]);       \
    gload16(sA[1] + ko, &Al[(bi)*16384 + (1 * 512 + wave * 64) * 8]);       \
    gload16(sB[0] + ko, &Bl[(bi)*8192 + (0 * 512 + wave * 64) * 8]); }
#define STG_H2(t_, bi)                                                      \
  { const size_t ko = (size_t)(t_) * 64;                                    \
    gload16(sA[2] + ko, &Al[(bi)*16384 + (2 * 512 + wave * 64) * 8]);       \
    gload16(sA[3] + ko, &Al[(bi)*16384 + (3 * 512 + wave * 64) * 8]);       \
    gload16(sB[1] + ko, &Bl[(bi)*8192 + (1 * 512 + wave * 64) * 8]); }

  const int sw = l15 & 7;
  const int c0 = (l4 ^ sw) << 4;
  const int c1 = ((4 + l4) ^ sw) << 4;
  const int rbA = (wr + l15) << 7;
  const int rbB = (wc + l15) << 7;

  f32x4 acc[4][4] = {};
  const int NT = K >> 6;

  STG_H1(0, 0); STG_H2(0, 0);
  STG_H1(1, 1); STG_H2(1, 1);

  int cur = 0;
  for (int t = 0; t < NT; ++t) {
    int sb = cur + 2; if (sb >= 3) sb -= 3;
    if (t + 1 < NT) { asm volatile("s_waitcnt vmcnt(6)" ::: "memory"); }
    else            { asm volatile("s_waitcnt vmcnt(0)" ::: "memory"); }
    __builtin_amdgcn_s_barrier();
    asm volatile("" ::: "memory");
    const char* Ab = (const char*)&Al[cur * 16384];
    const char* Bb = (const char*)&Bl[cur * 8192];
    bf16x8 b0[4], b1[4], aA[2][2], aB[2][2];
#pragma unroll
    for (int n = 0; n < 4; ++n) {
      b0[n] = *(const bf16x8*)(Bb + rbB + n * 2048 + c0);
      b1[n] = *(const bf16x8*)(Bb + rbB + n * 2048 + c1);
    }
#pragma unroll
    for (int m = 0; m < 2; ++m) {
      aA[m][0] = *(const bf16x8*)(Ab + rbA + m * 2048 + c0);
      aA[m][1] = *(const bf16x8*)(Ab + rbA + m * 2048 + c1);
    }
    if (t + 2 < NT) STG_H1(t + 2, sb);
    asm volatile("" ::: "memory");
    __builtin_amdgcn_s_barrier();
    asm volatile("" ::: "memory");
    __builtin_amdgcn_s_setprio(1);
#pragma unroll
    for (int m = 0; m < 2; ++m)
#pragma unroll
      for (int n = 0; n < 4; ++n) {
        acc[m][n] = MFMA16(aA[m][0], b0[n], acc[m][n]);
        acc[m][n] = MFMA16(aA[m][1], b1[n], acc[m][n]);
      }
    __builtin_amdgcn_s_setprio(0);
#pragma unroll
    for (int m = 0; m < 2; ++m) {
      aB[m][0] = *(const bf16x8*)(Ab + rbA + (m + 2) * 2048 + c0);
      aB[m][1] = *(const bf16x8*)(Ab + rbA + (m + 2) * 2048 + c1);
    }
    if (t + 2 < NT) STG_H2(t + 2, sb);
    asm volatile("" ::: "memory");
    __builtin_amdgcn_s_barrier();
    asm volatile("" ::: "memory");
    __builtin_amdgcn_s_setprio(1);
#pragma unroll
    for (int m = 0; m < 2; ++m)
#pragma unroll
      for (int n = 0; n < 4; ++n) {
        acc[m + 2][n] = MFMA16(aB[m][0], b0[n], acc[m + 2][n]);
        acc[m + 2][n] = MFMA16(aB[m][1], b1[n], acc[m + 2][n]);
      }
    __builtin_amdgcn_s_setprio(0);
    cur += 1; if (cur >= 3) cur = 0;
  }
#undef STG_H1
#undef STG_H2

#pragma unroll
  for (int m = 0; m < 4; ++m) {
#pragma unroll
    for (int n = 0; n < 4; ++n) {
      int row = row0 + wr + m * 16 + l4 * 4;
      int col = col0 + wc + n * 16 + l15;
#pragma unroll
      for (int r = 0; r < 4; ++r) {
        if (EPI == 0) {
          Cb[(size_t)(row + r) * N + col] = f2bf(acc[m][n][r]);
        } else if (EPI == 1) {
          Cf[(size_t)(row + r) * N + col] = acc[m][n][r] + bias[col];
        } else {
          if (col < 2048) Cb[(size_t)(row + r) * 2048 + col] = f2bf(acc[m][n][r]);
          else            Cb2[(size_t)(row + r) * 512 + col - 2048] = f2bf(acc[m][n][r]);
        }
      }
    }
  }
}

// O-proj: C = Ctx * WoT^T + bias (f32 out). XCD-chunk swizzle (256 = 8*32).
__global__ __launch_bounds__(512, 2) void gemm8p_o(
    const unsigned short* __restrict__ A, const unsigned short* __restrict__ B,
    float* __restrict__ Cf, const float* __restrict__ bias, int N, int K) {
  __shared__ unsigned short Al[3 * 256 * 64];
  __shared__ unsigned short Bl[3 * 128 * 64];
  int bid = (blockIdx.x & 7) * 32 + (blockIdx.x >> 3);
  g8p_core<1>(A, B, nullptr, nullptr, Cf, bias, N, K, bid, Al, Bl);
}

// Fused projections with segment-local XCD swizzle (320 = 8*40, 64 = 8*8).
__global__ __launch_bounds__(512, 2) void gemm_fused3(
    const unsigned short* __restrict__ Xb, const unsigned short* __restrict__ Bqk,
    unsigned short* __restrict__ Qb, unsigned short* __restrict__ Kb,
    const unsigned short* __restrict__ WvT, unsigned short* __restrict__ VTb) {
  __shared__ unsigned short Al[3 * 256 * 64];
  __shared__ unsigned short Bl[3 * 128 * 64];
  if (blockIdx.x < 320) {
    int bid = (blockIdx.x & 7) * 40 + (blockIdx.x >> 3);
    g8p_core<2>(Xb, Bqk, Qb, Kb, nullptr, nullptr, 2560, 2048, bid, Al, Bl);
  } else {
    int lb = blockIdx.x - 320;
    int bid = (lb & 7) * 8 + (lb >> 3);
    g8p_core<0>(WvT, Xb, VTb, nullptr, nullptr, nullptr, 4096, 2048, bid, Al, Bl);
  }
}

// ---------------- flash attention v7d: K staged in LDS, V direct from global ----------------
// 512 blocks x 256 thr (4 waves = 4 heads), KVBLK=64. K [64][128] double-buffered
// (32KB LDS, chunk-XOR swizzle). V read per-lane from global VT (L2/L1-resident:
// bg<->XCD gives 1MB working set/XCD) — removes 16 DS reads/iter/wave and all
// V staging (guide m169: don't stage what caches fit). Raw-domain softmax.
__global__ __launch_bounds__(256, 2) void flash_gqa7d(
    const unsigned short* __restrict__ Qb, const unsigned short* __restrict__ Kb,
    const unsigned short* __restrict__ VT, unsigned short* __restrict__ Ctx) {
  __shared__ unsigned short Sm[16384];  // 32KB: K buf0 @0, buf1 @8192 (ushort idx)

  const int tid = threadIdx.x;
  const int wave = tid >> 6, lane = tid & 63;
  const int l31 = lane & 31, hi = lane >> 5;
  const int i = blockIdx.x >> 3;   // 0..63
  const int bg = blockIdx.x & 7;   // 0..7 (bg <-> XCD)
  const int qt = (i < 32) ? i : (95 - i);
  const int b = bg >> 2, g = bg & 3;
  const int h = (g << 2) | wave;
  const int q0 = qt << 5;
  const int T = (qt >> 1) + 1;  // 64-kv tiles

  bf16x8 qf[8];
  {
    const unsigned short* qp =
        Qb + (size_t)(b * 2048 + q0 + l31) * 2048 + h * 128 + hi * 8;
#pragma unroll
    for (int ds = 0; ds < 8; ++ds) qf[ds] = *(const bf16x8*)(qp + ds * 16);
  }

  // K staging sources (pre-swizzled global; LDS linear — rule #21)
  const int cK = tid & 15, rK = tid >> 4;
  const unsigned short* kS0 = Kb + (size_t)(b * 2048 + rK +  0) * 512 + g * 128 + (cK ^ ((rK +  0) & 7)) * 8;
  const unsigned short* kS1 = Kb + (size_t)(b * 2048 + rK + 16) * 512 + g * 128 + (cK ^ ((rK + 16) & 7)) * 8;
  const unsigned short* kS2 = Kb + (size_t)(b * 2048 + rK + 32) * 512 + g * 128 + (cK ^ ((rK + 32) & 7)) * 8;
  const unsigned short* kS3 = Kb + (size_t)(b * 2048 + rK + 48) * 512 + g * 128 + (cK ^ ((rK + 48) & 7)) * 8;

  // V direct-read bases (element units); fragment = VT[(g*128+row)*4096 + b*2048
  //  + kv + ks*16 + hi*8], row = dblock*32 + l31.
  const unsigned short* vG0 = VT + (size_t)(g * 128 +  0 + l31) * 4096 + b * 2048 + hi * 8;
  const unsigned short* vG1 = VT + (size_t)(g * 128 + 32 + l31) * 4096 + b * 2048 + hi * 8;
  const unsigned short* vG2 = VT + (size_t)(g * 128 + 64 + l31) * 4096 + b * 2048 + hi * 8;
  const unsigned short* vG3 = VT + (size_t)(g * 128 + 96 + l31) * 4096 + b * 2048 + hi * 8;

#define STAGE7(t_, bi)                                          \
  {                                                             \
    unsigned short* kb_ = Sm + (bi)*8192;                       \
    const size_t ko_ = (size_t)(t_) * 64 * 512;                 \
    gload16(kS0 + ko_, kb_ + 0 * 2048 + wave * 512);            \
    gload16(kS1 + ko_, kb_ + 1 * 2048 + wave * 512);            \
    gload16(kS2 + ko_, kb_ + 2 * 2048 + wave * 512);            \
    gload16(kS3 + ko_, kb_ + 3 * 2048 + wave * 512);            \
  }

  const float s2 = 0.12751744f;  // 1/sqrt(128) * log2(e)
  float m_r = -1e30f, l_r = 0.f;  // m_r in RAW score units
  f32x16 o0 = {}, o1 = {}, o2 = {}, o3 = {};

  STAGE7(0, 0);
  __syncthreads();

  for (int t = 0; t < T; ++t) {
    const int buf = t & 1;
    if (t + 1 < T) STAGE7(t + 1, buf ^ 1);
    const char* Kl = (const char*)Sm + buf * 16384;
    const int kv = t << 6;
    const unsigned short* vP0 = vG0 + kv;
    const unsigned short* vP1 = vG1 + kv;
    const unsigned short* vP2 = vG2 + kv;
    const unsigned short* vP3 = vG3 + kv;
    // ---- S^T = K Q^T (raw scores) ----
    f32x16 st0 = {}, st1 = {};
    __builtin_amdgcn_s_setprio(1);
#pragma unroll
    for (int ds = 0; ds < 8; ++ds) {
      const int c = ds * 32 + hi * 16;
      const int by0 = (l31 * 256 + c) ^ ((l31 & 7) << 4);
      const int by1 = ((32 + l31) * 256 + c) ^ ((l31 & 7) << 4);
      bf16x8 kf0 = *(const bf16x8*)(Kl + by0);
      bf16x8 kf1 = *(const bf16x8*)(Kl + by1);
      st0 = MFMA32(kf0, qf[ds], st0);
      st1 = MFMA32(kf1, qf[ds], st1);
    }
    __builtin_amdgcn_s_setprio(0);
    // ---- causal mask (raw domain; diagonal pair-tile only) ----
    const int q_abs = q0 + l31;
    if (kv + 64 > q0) {
#pragma unroll
      for (int rr = 0; rr < 16; ++rr) {
        const int koff = (rr & 3) + 8 * (rr >> 2) + 4 * hi;
        if (kv + koff > q_abs) st0[rr] = -1e30f;
        if (kv + 32 + koff > q_abs) st1[rr] = -1e30f;
      }
    }
    // ---- row max ----
    float pm = st0[0];
#pragma unroll
    for (int rr = 1; rr < 16; ++rr) pm = fmaxf(pm, st0[rr]);
#pragma unroll
    for (int rr = 0; rr < 16; ++rr) pm = fmaxf(pm, st1[rr]);
    pm = fmaxf(pm, __shfl_xor(pm, 32));
    // ---- online softmax (defer-max T13; raw threshold 90 = 11.5/s2) ----
    if (!__all(pm - m_r <= 90.0f)) {
      const float mn = fmaxf(m_r, pm);
      const float osc = exp2f((m_r - mn) * s2);
      m_r = mn;
      l_r *= osc;
#pragma unroll
      for (int rr = 0; rr < 16; ++rr) {
        o0[rr] *= osc; o1[rr] *= osc; o2[rr] *= osc; o3[rr] *= osc;
      }
    }
    const float cfold = -m_r * s2;
    float ps = 0.f;
#pragma unroll
    for (int rr = 0; rr < 16; ++rr) { st0[rr] = exp2f(fmaf(st0[rr], s2, cfold)); ps += st0[rr]; }
#pragma unroll
    for (int rr = 0; rr < 16; ++rr) { st1[rr] = exp2f(fmaf(st1[rr], s2, cfold)); ps += st1[rr]; }
    ps += __shfl_xor(ps, 32);
    l_r += ps;
    // ---- pack P rows ----
    unsigned w0[8], w1[8];
#pragma unroll
    for (int rp = 0; rp < 8; ++rp) {
      w0[rp] = pk2(st0[2 * rp], st0[2 * rp + 1]);
      w1[rp] = pk2(st1[2 * rp], st1[2 * rp + 1]);
    }
    // ---- O^T += V^T P^T : V fragments direct from global (L2/L1-hit) ----
    __builtin_amdgcn_s_setprio(1);
#define PV_KS(ks, W)                                                          \
    {                                                                         \
      const int k4 = ((ks) & 1) * 4;                                          \
      unsigned a0 = W[k4], a1 = W[k4 + 1], b0 = W[k4 + 2], b1 = W[k4 + 3];    \
      unsigned q0_ = hi ? a0 : b0, q1_ = hi ? a1 : b1;                        \
      unsigned e0 = (unsigned)__shfl_xor((int)q0_, 32);                       \
      unsigned e1 = (unsigned)__shfl_xor((int)q1_, 32);                       \
      union { u32x4 u; bf16x8 v; } pk;                                        \
      pk.u[0] = hi ? e0 : a0; pk.u[1] = hi ? e1 : a1;                         \
      pk.u[2] = hi ? b0 : e0; pk.u[3] = hi ? b1 : e1;                         \
      { bf16x8 vf = *(const bf16x8*)(vP0 + (ks)*16); o0 = MFMA32(vf, pk.v, o0); } \
      { bf16x8 vf = *(const bf16x8*)(vP1 + (ks)*16); o1 = MFMA32(vf, pk.v, o1); } \
      { bf16x8 vf = *(const bf16x8*)(vP2 + (ks)*16); o2 = MFMA32(vf, pk.v, o2); } \
      { bf16x8 vf = *(const bf16x8*)(vP3 + (ks)*16); o3 = MFMA32(vf, pk.v, o3); } \
    }
    PV_KS(0, w0) PV_KS(1, w0) PV_KS(2, w1) PV_KS(3, w1)
#undef PV_KS
    __builtin_amdgcn_s_setprio(0);
    __syncthreads();
  }
#undef STAGE7

  // ---- finalize ----
  const float inv = 1.f / l_r;
  unsigned short* cp = Ctx + (size_t)(b * 2048 + q0 + l31) * 2048 + h * 128;
#pragma unroll
  for (int a = 0; a < 4; ++a) {
    ushort4 p0, p1, p2, p3;
    p0.x = f2bf(o0[4 * a + 0] * inv); p0.y = f2bf(o0[4 * a + 1] * inv);
    p0.z = f2bf(o0[4 * a + 2] * inv); p0.w = f2bf(o0[4 * a + 3] * inv);
    p1.x = f2bf(o1[4 * a + 0] * inv); p1.y = f2bf(o1[4 * a + 1] * inv);
    p1.z = f2bf(o1[4 * a + 2] * inv); p1.w = f2bf(o1[4 * a + 3] * inv);
    p2.x = f2bf(o2[4 * a + 0] * inv); p2.y = f2bf(o2[4 * a + 1] * inv);
    p2.z = f2bf(o2[4 * a + 2] * inv); p2.w = f2bf(o2[4 * a + 3] * inv);
    p3.x = f2bf(o3[4 * a + 0] * inv); p3.y = f2bf(o3[4 * a + 1] * inv);
    p3.z = f2bf(o3[4 * a + 2] * inv); p3.w = f2bf(o3[4 * a + 3] * inv);
    const int cc = 8 * a + 4 * hi;
    *(ushort4*)(cp + 0 * 32 + cc) = p0;
    *(ushort4*)(cp + 1 * 32 + cc) = p1;
    *(ushort4*)(cp + 2 * 32 + cc) = p2;
    *(ushort4*)(cp + 3 * 32 + cc) = p3;
  }
}

// ---------------- launch ----------------
extern "C" void kernel_launch(void* const* d_in, const int* in_sizes, int n_in,
                              void* d_out, int out_size, void* d_ws, size_t ws_size,
                              hipStream_t stream) {
  (void)in_sizes; (void)n_in; (void)out_size; (void)ws_size;
  const float* x  = (const float*)d_in[0];
  const float* Wq = (const float*)d_in[1];
  const float* Wk = (const float*)d_in[2];
  const float* Wv = (const float*)d_in[3];
  const float* Wo = (const float*)d_in[4];
  const float* bo = (const float*)d_in[5];
  float* out = (float*)d_out;

  unsigned short* Xb  = (unsigned short*)d_ws;            // [4096,2048]
  unsigned short* WqT = Xb  + (size_t)4096 * 2048;        // [2048,2048]
  unsigned short* WkT = WqT + (size_t)2048 * 2048;        // [512,2048]
  unsigned short* WvT = WkT + (size_t)512 * 2048;         // [512,2048]
  unsigned short* WoT = WvT + (size_t)512 * 2048;         // [2048,2048]
  unsigned short* Qb  = WoT + (size_t)2048 * 2048;        // [4096,2048]
  unsigned short* Kb  = Qb  + (size_t)4096 * 2048;        // [4096,512]
  unsigned short* VTb = Kb  + (size_t)4096 * 512;         // [512,4096]
  unsigned short* Ctx = VTb + (size_t)512 * 4096;         // [4096,2048]

  prep_all2<<<12288, 256, 0, stream>>>(x, Xb, Wq, Wk, Wv, Wo, WqT, WkT, WvT, WoT);

  gemm_fused3<<<dim3(384), 512, 0, stream>>>(Xb, WqT, Qb, Kb, WvT, VTb);

  flash_gqa7d<<<dim3(512), 256, 0, stream>>>(Qb, Kb, VTb, Ctx);

  gemm8p_o<<<dim3(256), 512, 0, stream>>>(Ctx, WoT, out, bo, 2048, 2048);
}

// Round 15
// 191.191 us; speedup vs baseline: 1.2596x; 1.2596x over previous
//
#include <hip/hip_runtime.h>
#include <hip/hip_bf16.h>

typedef short bf16x8 __attribute__((ext_vector_type(8)));
typedef float f32x4 __attribute__((ext_vector_type(4)));
typedef float f32x16 __attribute__((ext_vector_type(16)));
typedef unsigned int u32x4 __attribute__((ext_vector_type(4)));

#define MFMA16(a, b, c) __builtin_amdgcn_mfma_f32_16x16x32_bf16((a), (b), (c), 0, 0, 0)
#define MFMA32(a, b, c) __builtin_amdgcn_mfma_f32_32x32x16_bf16((a), (b), (c), 0, 0, 0)

static __device__ __forceinline__ unsigned short f2bf(float f) {
  union { float f; unsigned u; } v;
  v.f = f;
  unsigned r = (v.u + 0x7FFFu + ((v.u >> 16) & 1u)) >> 16;
  return (unsigned short)r;
}

// round-half-up pack of two f32 -> bf16x2 word
static __device__ __forceinline__ unsigned pk2(float a, float b) {
  unsigned ua = __float_as_uint(a) + 0x8000u;
  unsigned ub = __float_as_uint(b) + 0x8000u;
  return (ua >> 16) | (ub & 0xFFFF0000u);
}

static __device__ __forceinline__ void gload16(const void* g, void* l) {
  __builtin_amdgcn_global_load_lds(
      (const __attribute__((address_space(1))) unsigned int*)g,
      (__attribute__((address_space(3))) unsigned int*)l, 16, 0, 0);
}

// ---------------- prep: 4 weight transposes + x cast, one launch ----------------
__global__ __launch_bounds__(256) void prep_all2(
    const float* __restrict__ x, unsigned short* __restrict__ Xb,
    const float* __restrict__ Wq, const float* __restrict__ Wk,
    const float* __restrict__ Wv, const float* __restrict__ Wo,
    unsigned short* __restrict__ WqT, unsigned short* __restrict__ WkT,
    unsigned short* __restrict__ WvT, unsigned short* __restrict__ WoT) {
  int id = blockIdx.x;
  if (id >= 10240) {
    const int n4 = (4096 * 2048) / 4;
    const int stride = 2048 * 256;
    for (int i = (id - 10240) * 256 + threadIdx.x; i < n4; i += stride) {
      float4 v = reinterpret_cast<const float4*>(x)[i];
      ushort4 o;
      o.x = f2bf(v.x); o.y = f2bf(v.y); o.z = f2bf(v.z); o.w = f2bf(v.w);
      reinterpret_cast<ushort4*>(Xb)[i] = o;
    }
    return;
  }
  __shared__ float tile[32][33];
  const float* src; unsigned short* dst; int R, C, bx, by;
  if (id < 4096)      { src = Wq; dst = WqT; R = 2048; C = 2048; bx = id & 63; by = id >> 6; }
  else if (id < 5120) { id -= 4096; src = Wk; dst = WkT; R = 2048; C = 512; bx = id & 15; by = id >> 4; }
  else if (id < 6144) { id -= 5120; src = Wv; dst = WvT; R = 2048; C = 512; bx = id & 15; by = id >> 4; }
  else                { id -= 6144; src = Wo; dst = WoT; R = 2048; C = 2048; bx = id & 63; by = id >> 6; }
  int tx = threadIdx.x & 31;
  int ty = threadIdx.x >> 5;
  int r0 = by * 32, c0 = bx * 32;
#pragma unroll
  for (int i = 0; i < 32; i += 8)
    tile[ty + i][tx] = src[(size_t)(r0 + ty + i) * C + (c0 + tx)];
  __syncthreads();
#pragma unroll
  for (int i = 0; i < 32; i += 8)
    dst[(size_t)(c0 + ty + i) * R + (r0 + tx)] = f2bf(tile[tx][ty + i]);
}

// ---------------- pipelined GEMM core: BM=256, BN=128, BK=64 ----------------
template <int EPI>
static __device__ __forceinline__ void g8p_core(
    const unsigned short* __restrict__ A, const unsigned short* __restrict__ B,
    unsigned short* __restrict__ Cb, unsigned short* __restrict__ Cb2,
    float* __restrict__ Cf, const float* __restrict__ bias,
    int N, int K, int bid, unsigned short* Al, unsigned short* Bl) {
  const int tid = threadIdx.x;
  const int wave = tid >> 6, lane = tid & 63;
  const int l15 = lane & 15, l4 = lane >> 4;
  const int tilesN = N >> 7;
  const int bm = bid / tilesN, bn = bid % tilesN;
  const int row0 = bm << 8, col0 = bn << 7;
  const int wr = (wave >> 1) << 6;
  const int wc = (wave & 1) << 6;

  const unsigned short* sA[4];
  const unsigned short* sB[2];
#pragma unroll
  for (int i = 0; i < 4; ++i) {
    int q = i * 512 + wave * 64 + lane;
    int r = q >> 3, c = (q & 7) ^ (r & 7);
    sA[i] = A + (size_t)(row0 + r) * K + c * 8;
  }
#pragma unroll
  for (int i = 0; i < 2; ++i) {
    int q = i * 512 + wave * 64 + lane;
    int r = q >> 3, c = (q & 7) ^ (r & 7);
    sB[i] = B + (size_t)(col0 + r) * K + c * 8;
  }

#define STG_H1(t_, bi)                                                      \
  { const size_t ko = (size_t)(t_) * 64;                                    \
    gload16(sA[0] + ko, &Al[(bi)*16384 + (0 * 512 + wave * 64) * 8]);       \
    gload16(sA[1] + ko, &Al[(bi)*16384 + (1 * 512 + wave * 64) * 8]);       \
    gload16(sB[0] + ko, &Bl[(bi)*8192 + (0 * 512 + wave * 64) * 8]); }
#define STG_H2(t_, bi)                                                      \
  { const size_t ko = (size_t)(t_) * 64;                                    \
    gload16(sA[2] + ko, &Al[(bi)*16384 + (2 * 512 + wave * 64) * 8]);       \
    gload16(sA[3] + ko, &Al[(bi)*16384 + (3 * 512 + wave * 64) * 8]);       \
    gload16(sB[1] + ko, &Bl[(bi)*8192 + (1 * 512 + wave * 64) * 8]); }

  const int sw = l15 & 7;
  const int c0 = (l4 ^ sw) << 4;
  const int c1 = ((4 + l4) ^ sw) << 4;
  const int rbA = (wr + l15) << 7;
  const int rbB = (wc + l15) << 7;

  f32x4 acc[4][4] = {};
  const int NT = K >> 6;

  STG_H1(0, 0); STG_H2(0, 0);
  STG_H1(1, 1); STG_H2(1, 1);

  int cur = 0;
  for (int t = 0; t < NT; ++t) {
    int sb = cur + 2; if (sb >= 3) sb -= 3;
    if (t + 1 < NT) { asm volatile("s_waitcnt vmcnt(6)" ::: "memory"); }
    else            { asm volatile("s_waitcnt vmcnt(0)" ::: "memory"); }
    __builtin_amdgcn_s_barrier();
    asm volatile("" ::: "memory");
    const char* Ab = (const char*)&Al[cur * 16384];
    const char* Bb = (const char*)&Bl[cur * 8192];
    bf16x8 b0[4], b1[4], aA[2][2], aB[2][2];
#pragma unroll
    for (int n = 0; n < 4; ++n) {
      b0[n] = *(const bf16x8*)(Bb + rbB + n * 2048 + c0);
      b1[n] = *(const bf16x8*)(Bb + rbB + n * 2048 + c1);
    }
#pragma unroll
    for (int m = 0; m < 2; ++m) {
      aA[m][0] = *(const bf16x8*)(Ab + rbA + m * 2048 + c0);
      aA[m][1] = *(const bf16x8*)(Ab + rbA + m * 2048 + c1);
    }
    if (t + 2 < NT) STG_H1(t + 2, sb);
    asm volatile("" ::: "memory");
    __builtin_amdgcn_s_barrier();
    asm volatile("" ::: "memory");
    __builtin_amdgcn_s_setprio(1);
#pragma unroll
    for (int m = 0; m < 2; ++m)
#pragma unroll
      for (int n = 0; n < 4; ++n) {
        acc[m][n] = MFMA16(aA[m][0], b0[n], acc[m][n]);
        acc[m][n] = MFMA16(aA[m][1], b1[n], acc[m][n]);
      }
    __builtin_amdgcn_s_setprio(0);
#pragma unroll
    for (int m = 0; m < 2; ++m) {
      aB[m][0] = *(const bf16x8*)(Ab + rbA + (m + 2) * 2048 + c0);
      aB[m][1] = *(const bf16x8*)(Ab + rbA + (m + 2) * 2048 + c1);
    }
    if (t + 2 < NT) STG_H2(t + 2, sb);
    asm volatile("" ::: "memory");
    __builtin_amdgcn_s_barrier();
    asm volatile("" ::: "memory");
    __builtin_amdgcn_s_setprio(1);
#pragma unroll
    for (int m = 0; m < 2; ++m)
#pragma unroll
      for (int n = 0; n < 4; ++n) {
        acc[m + 2][n] = MFMA16(aB[m][0], b0[n], acc[m + 2][n]);
        acc[m + 2][n] = MFMA16(aB[m][1], b1[n], acc[m + 2][n]);
      }
    __builtin_amdgcn_s_setprio(0);
    cur += 1; if (cur >= 3) cur = 0;
  }
#undef STG_H1
#undef STG_H2

#pragma unroll
  for (int m = 0; m < 4; ++m) {
#pragma unroll
    for (int n = 0; n < 4; ++n) {
      int row = row0 + wr + m * 16 + l4 * 4;
      int col = col0 + wc + n * 16 + l15;
#pragma unroll
      for (int r = 0; r < 4; ++r) {
        if (EPI == 0) {
          Cb[(size_t)(row + r) * N + col] = f2bf(acc[m][n][r]);
        } else if (EPI == 1) {
          Cf[(size_t)(row + r) * N + col] = acc[m][n][r] + bias[col];
        } else {
          if (col < 2048) Cb[(size_t)(row + r) * 2048 + col] = f2bf(acc[m][n][r]);
          else            Cb2[(size_t)(row + r) * 512 + col - 2048] = f2bf(acc[m][n][r]);
        }
      }
    }
  }
}

// O-proj: C = Ctx * WoT^T + bias (f32 out). XCD-chunk swizzle (256 = 8*32).
__global__ __launch_bounds__(512, 2) void gemm8p_o(
    const unsigned short* __restrict__ A, const unsigned short* __restrict__ B,
    float* __restrict__ Cf, const float* __restrict__ bias, int N, int K) {
  __shared__ unsigned short Al[3 * 256 * 64];
  __shared__ unsigned short Bl[3 * 128 * 64];
  int bid = (blockIdx.x & 7) * 32 + (blockIdx.x >> 3);
  g8p_core<1>(A, B, nullptr, nullptr, Cf, bias, N, K, bid, Al, Bl);
}

// Fused projections with segment-local XCD swizzle (320 = 8*40, 64 = 8*8).
__global__ __launch_bounds__(512, 2) void gemm_fused3(
    const unsigned short* __restrict__ Xb, const unsigned short* __restrict__ Bqk,
    unsigned short* __restrict__ Qb, unsigned short* __restrict__ Kb,
    const unsigned short* __restrict__ WvT, unsigned short* __restrict__ VTb) {
  __shared__ unsigned short Al[3 * 256 * 64];
  __shared__ unsigned short Bl[3 * 128 * 64];
  if (blockIdx.x < 320) {
    int bid = (blockIdx.x & 7) * 40 + (blockIdx.x >> 3);
    g8p_core<2>(Xb, Bqk, Qb, Kb, nullptr, nullptr, 2560, 2048, bid, Al, Bl);
  } else {
    int lb = blockIdx.x - 320;
    int bid = (lb & 7) * 8 + (lb >> 3);
    g8p_core<0>(WvT, Xb, VTb, nullptr, nullptr, nullptr, 4096, 2048, bid, Al, Bl);
  }
}

// ---------------- flash attention v7c (R13 proven: 77.8us) ----------------
// 512 blocks x 256 thr (4 waves = 4 heads). KVBLK=64, 64KB LDS double-buffered
// (K [64][128] + V^T [128][64], chunk-XOR swizzle both-sides). Raw-domain
// softmax (scale folded into exp2 via fma), defer-max T13, pk2 pack, shfl
// cross-half exchange, setprio on MFMA clusters.
__global__ __launch_bounds__(256, 2) void flash_gqa7c(
    const unsigned short* __restrict__ Qb, const unsigned short* __restrict__ Kb,
    const unsigned short* __restrict__ VT, unsigned short* __restrict__ Ctx) {
  __shared__ unsigned short Sm[32768];  // bytes: K0@0 K1@16384 V0@32768 V1@49152

  const int tid = threadIdx.x;
  const int wave = tid >> 6, lane = tid & 63;
  const int l31 = lane & 31, hi = lane >> 5;
  const int i = blockIdx.x >> 3;   // 0..63
  const int bg = blockIdx.x & 7;   // 0..7
  const int qt = (i < 32) ? i : (95 - i);
  const int b = bg >> 2, g = bg & 3;
  const int h = (g << 2) | wave;
  const int q0 = qt << 5;
  const int T = (qt >> 1) + 1;  // 64-kv tiles

  bf16x8 qf[8];
  {
    const unsigned short* qp =
        Qb + (size_t)(b * 2048 + q0 + l31) * 2048 + h * 128 + hi * 8;
#pragma unroll
    for (int ds = 0; ds < 8; ++ds) qf[ds] = *(const bf16x8*)(qp + ds * 16);
  }

  const int cK = tid & 15, rK = tid >> 4;
  const unsigned short* kS0 = Kb + (size_t)(b * 2048 + rK +  0) * 512 + g * 128 + (cK ^ ((rK +  0) & 7)) * 8;
  const unsigned short* kS1 = Kb + (size_t)(b * 2048 + rK + 16) * 512 + g * 128 + (cK ^ ((rK + 16) & 7)) * 8;
  const unsigned short* kS2 = Kb + (size_t)(b * 2048 + rK + 32) * 512 + g * 128 + (cK ^ ((rK + 32) & 7)) * 8;
  const unsigned short* kS3 = Kb + (size_t)(b * 2048 + rK + 48) * 512 + g * 128 + (cK ^ ((rK + 48) & 7)) * 8;
  const int cV = tid & 7, rV = tid >> 3;
  const unsigned short* vS0 = VT + (size_t)(g * 128 + rV +  0) * 4096 + b * 2048 + (cV ^ ((rV +  0) & 7)) * 8;
  const unsigned short* vS1 = VT + (size_t)(g * 128 + rV + 32) * 4096 + b * 2048 + (cV ^ ((rV + 32) & 7)) * 8;
  const unsigned short* vS2 = VT + (size_t)(g * 128 + rV + 64) * 4096 + b * 2048 + (cV ^ ((rV + 64) & 7)) * 8;
  const unsigned short* vS3 = VT + (size_t)(g * 128 + rV + 96) * 4096 + b * 2048 + (cV ^ ((rV + 96) & 7)) * 8;

#define STAGE7(t_, bi)                                          \
  {                                                             \
    unsigned short* kb_ = Sm + (bi)*8192;                       \
    unsigned short* vb_ = Sm + 16384 + (bi)*8192;               \
    const size_t ko_ = (size_t)(t_) * 64 * 512;                 \
    const size_t vo_ = (size_t)(t_) * 64;                       \
    gload16(kS0 + ko_, kb_ + 0 * 2048 + wave * 512);            \
    gload16(kS1 + ko_, kb_ + 1 * 2048 + wave * 512);            \
    gload16(kS2 + ko_, kb_ + 2 * 2048 + wave * 512);            \
    gload16(kS3 + ko_, kb_ + 3 * 2048 + wave * 512);            \
    gload16(vS0 + vo_, vb_ + 0 * 2048 + wave * 512);            \
    gload16(vS1 + vo_, vb_ + 1 * 2048 + wave * 512);            \
    gload16(vS2 + vo_, vb_ + 2 * 2048 + wave * 512);            \
    gload16(vS3 + vo_, vb_ + 3 * 2048 + wave * 512);            \
  }

  const float s2 = 0.12751744f;  // 1/sqrt(128) * log2(e)
  float m_r = -1e30f, l_r = 0.f;  // m_r in RAW score units
  f32x16 o0 = {}, o1 = {}, o2 = {}, o3 = {};

  STAGE7(0, 0);
  __syncthreads();

  for (int t = 0; t < T; ++t) {
    const int buf = t & 1;
    if (t + 1 < T) STAGE7(t + 1, buf ^ 1);
    const char* Kl = (const char*)Sm + buf * 16384;
    const char* Vl = (const char*)Sm + 32768 + buf * 16384;
    const int kv = t << 6;
    // ---- S^T = K Q^T (raw scores) ----
    f32x16 st0 = {}, st1 = {};
    __builtin_amdgcn_s_setprio(1);
#pragma unroll
    for (int ds = 0; ds < 8; ++ds) {
      const int c = ds * 32 + hi * 16;
      const int by0 = (l31 * 256 + c) ^ ((l31 & 7) << 4);
      const int by1 = ((32 + l31) * 256 + c) ^ ((l31 & 7) << 4);
      bf16x8 kf0 = *(const bf16x8*)(Kl + by0);
      bf16x8 kf1 = *(const bf16x8*)(Kl + by1);
      st0 = MFMA32(kf0, qf[ds], st0);
      st1 = MFMA32(kf1, qf[ds], st1);
    }
    __builtin_amdgcn_s_setprio(0);
    // ---- causal mask (raw domain; diagonal pair-tile only) ----
    const int q_abs = q0 + l31;
    if (kv + 64 > q0) {
#pragma unroll
      for (int rr = 0; rr < 16; ++rr) {
        const int koff = (rr & 3) + 8 * (rr >> 2) + 4 * hi;
        if (kv + koff > q_abs) st0[rr] = -1e30f;
        if (kv + 32 + koff > q_abs) st1[rr] = -1e30f;
      }
    }
    // ---- row max (raw; in-lane + shfl cross-half) ----
    float pm = st0[0];
#pragma unroll
    for (int rr = 1; rr < 16; ++rr) pm = fmaxf(pm, st0[rr]);
#pragma unroll
    for (int rr = 0; rr < 16; ++rr) pm = fmaxf(pm, st1[rr]);
    pm = fmaxf(pm, __shfl_xor(pm, 32));
    // ---- online softmax (defer-max T13; raw threshold 90 = 11.5/s2) ----
    if (!__all(pm - m_r <= 90.0f)) {
      const float mn = fmaxf(m_r, pm);
      const float osc = exp2f((m_r - mn) * s2);
      m_r = mn;
      l_r *= osc;
#pragma unroll
      for (int rr = 0; rr < 16; ++rr) {
        o0[rr] *= osc; o1[rr] *= osc; o2[rr] *= osc; o3[rr] *= osc;
      }
    }
    const float cfold = -m_r * s2;
    float ps = 0.f;
#pragma unroll
    for (int rr = 0; rr < 16; ++rr) { st0[rr] = exp2f(fmaf(st0[rr], s2, cfold)); ps += st0[rr]; }
#pragma unroll
    for (int rr = 0; rr < 16; ++rr) { st1[rr] = exp2f(fmaf(st1[rr], s2, cfold)); ps += st1[rr]; }
    ps += __shfl_xor(ps, 32);
    l_r += ps;
    // ---- pack P rows ----
    unsigned w0[8], w1[8];
#pragma unroll
    for (int rp = 0; rp < 8; ++rp) {
      w0[rp] = pk2(st0[2 * rp], st0[2 * rp + 1]);
      w1[rp] = pk2(st1[2 * rp], st1[2 * rp + 1]);
    }
    // ---- O^T += V^T P^T ----
    __builtin_amdgcn_s_setprio(1);
#define PV_KS(ks, W)                                                          \
    {                                                                         \
      const int k4 = ((ks) & 1) * 4;                                          \
      unsigned a0 = W[k4], a1 = W[k4 + 1], b0 = W[k4 + 2], b1 = W[k4 + 3];    \
      unsigned q0_ = hi ? a0 : b0, q1_ = hi ? a1 : b1;                        \
      unsigned e0 = (unsigned)__shfl_xor((int)q0_, 32);                       \
      unsigned e1 = (unsigned)__shfl_xor((int)q1_, 32);                       \
      union { u32x4 u; bf16x8 v; } pk;                                        \
      pk.u[0] = hi ? e0 : a0; pk.u[1] = hi ? e1 : a1;                         \
      pk.u[2] = hi ? b0 : e0; pk.u[3] = hi ? b1 : e1;                         \
      const int cb = (ks)*32 + hi * 16;                                       \
      { const int row = l31;      const int by = (row * 128 + cb) ^ ((row & 7) << 4); \
        bf16x8 vf = *(const bf16x8*)(Vl + by); o0 = MFMA32(vf, pk.v, o0); }   \
      { const int row = 32 + l31; const int by = (row * 128 + cb) ^ ((row & 7) << 4); \
        bf16x8 vf = *(const bf16x8*)(Vl + by); o1 = MFMA32(vf, pk.v, o1); }   \
      { const int row = 64 + l31; const int by = (row * 128 + cb) ^ ((row & 7) << 4); \
        bf16x8 vf = *(const bf16x8*)(Vl + by); o2 = MFMA32(vf, pk.v, o2); }   \
      { const int row = 96 + l31; const int by = (row * 128 + cb) ^ ((row & 7) << 4); \
        bf16x8 vf = *(const bf16x8*)(Vl + by); o3 = MFMA32(vf, pk.v, o3); }   \
    }
    PV_KS(0, w0) PV_KS(1, w0) PV_KS(2, w1) PV_KS(3, w1)
#undef PV_KS
    __builtin_amdgcn_s_setprio(0);
    __syncthreads();
  }
#undef STAGE7

  // ---- finalize ----
  const float inv = 1.f / l_r;
  unsigned short* cp = Ctx + (size_t)(b * 2048 + q0 + l31) * 2048 + h * 128;
#pragma unroll
  for (int a = 0; a < 4; ++a) {
    ushort4 p0, p1, p2, p3;
    p0.x = f2bf(o0[4 * a + 0] * inv); p0.y = f2bf(o0[4 * a + 1] * inv);
    p0.z = f2bf(o0[4 * a + 2] * inv); p0.w = f2bf(o0[4 * a + 3] * inv);
    p1.x = f2bf(o1[4 * a + 0] * inv); p1.y = f2bf(o1[4 * a + 1] * inv);
    p1.z = f2bf(o1[4 * a + 2] * inv); p1.w = f2bf(o1[4 * a + 3] * inv);
    p2.x = f2bf(o2[4 * a + 0] * inv); p2.y = f2bf(o2[4 * a + 1] * inv);
    p2.z = f2bf(o2[4 * a + 2] * inv); p2.w = f2bf(o2[4 * a + 3] * inv);
    p3.x = f2bf(o3[4 * a + 0] * inv); p3.y = f2bf(o3[4 * a + 1] * inv);
    p3.z = f2bf(o3[4 * a + 2] * inv); p3.w = f2bf(o3[4 * a + 3] * inv);
    const int cc = 8 * a + 4 * hi;
    *(ushort4*)(cp + 0 * 32 + cc) = p0;
    *(ushort4*)(cp + 1 * 32 + cc) = p1;
    *(ushort4*)(cp + 2 * 32 + cc) = p2;
    *(ushort4*)(cp + 3 * 32 + cc) = p3;
  }
}

// ---------------- launch ----------------
extern "C" void kernel_launch(void* const* d_in, const int* in_sizes, int n_in,
                              void* d_out, int out_size, void* d_ws, size_t ws_size,
                              hipStream_t stream) {
  (void)in_sizes; (void)n_in; (void)out_size; (void)ws_size;
  const float* x  = (const float*)d_in[0];
  const float* Wq = (const float*)d_in[1];
  const float* Wk = (const float*)d_in[2];
  const float* Wv = (const float*)d_in[3];
  const float* Wo = (const float*)d_in[4];
  const float* bo = (const float*)d_in[5];
  float* out = (float*)d_out;

  unsigned short* Xb  = (unsigned short*)d_ws;            // [4096,2048]
  unsigned short* WqT = Xb  + (size_t)4096 * 2048;        // [2048,2048]
  unsigned short* WkT = WqT + (size_t)2048 * 2048;        // [512,2048]
  unsigned short* WvT = WkT + (size_t)512 * 2048;         // [512,2048]
  unsigned short* WoT = WvT + (size_t)512 * 2048;         // [2048,2048]
  unsigned short* Qb  = WoT + (size_t)2048 * 2048;        // [4096,2048]
  unsigned short* Kb  = Qb  + (size_t)4096 * 2048;        // [4096,512]
  unsigned short* VTb = Kb  + (size_t)4096 * 512;         // [512,4096]
  unsigned short* Ctx = VTb + (size_t)512 * 4096;         // [4096,2048]

  prep_all2<<<12288, 256, 0, stream>>>(x, Xb, Wq, Wk, Wv, Wo, WqT, WkT, WvT, WoT);

  gemm_fused3<<<dim3(384), 512, 0, stream>>>(Xb, WqT, Qb, Kb, WvT, VTb);

  flash_gqa7c<<<dim3(512), 256, 0, stream>>>(Qb, Kb, VTb, Ctx);

  gemm8p_o<<<dim3(256), 512, 0, stream>>>(Ctx, WoT, out, bo, 2048, 2048);
}